// Round 13
// baseline (163.107 us; speedup 1.0000x reference)
//
#include <hip/hip_runtime.h>
#include <stdint.h>

// DCNv2 forward, MI355X — R24: barrier-free lane-aligned fused_gemm,
//  COMPILER-managed loads (no asm, no manual vmcnt).
//  R23 (same structure + asm-pinned loads + hand ledger) SIGABRT'd; audit
//  found no semantic bug => suspect the asm/ledger machinery itself. R24
//  keeps the structural win and deletes the machinery:
//   - lane l's A-frag for mfma 16x16x32 is row (l&15), k-chunk (l>>4)*8:
//     each lane gathers its 4 corners (16B) and bilinears DIRECTLY into its
//     MFMA A operand. No LDS A, no ds_write/read, no swizzle, NO barrier
//     after the prologue — the 72-tile loop is ONE scheduling region, where
//     the compiler's own counted-waitcnt insertion is near-optimal (m97).
//   - named even/odd register rotation (loop-carried) forces issue-ahead;
//     compiler emits precise vmcnt for first use.
//  Wave = 16 rows x 256 cols; 4 waves/block, grid 256, 1 wave/SIMD,
//  launch_bounds(256,1) => 512 VGPR budget (~280 needed).
//  Floor: B 64KB/CU/tile through L1 ~512cy + gathers => fused ~26-30us.
//  K0 prep_and_transpose, K1 offset_conv_sk, K2 index_prep unchanged (R22).

#define CIN 256
#define COUT 256
#define HWS 4096      // H*W
#define MTOT 16384    // B*H*W
#define KTOT 2304     // CIN*9
#define SPLITK 8

typedef __attribute__((ext_vector_type(8))) short bf16x8;
typedef __attribute__((ext_vector_type(4))) float f32x4;

__device__ __forceinline__ unsigned short f2bf(float f) {
  unsigned int u = __float_as_uint(f);
  unsigned int r = (u + 0x7fffu + ((u >> 16) & 1u)) >> 16;
  return (unsigned short)r;
}
__device__ __forceinline__ float bf2f(unsigned short u) {
  return __uint_as_float(((unsigned int)u) << 16);
}
// bf16 pair unpack: 1 VALU each.
__device__ __forceinline__ float bflo(unsigned int u) { return __uint_as_float(u << 16); }
__device__ __forceinline__ float bfhi(unsigned int u) { return __uint_as_float(u & 0xffff0000u); }

__device__ __forceinline__ void gload_lds16(const void* g, void* l) {
  __builtin_amdgcn_global_load_lds((const __attribute__((address_space(1))) void*)g,
                                   (__attribute__((address_space(3))) void*)l, 16, 0, 0);
}

// ---------------- K0: fused transpose + weight prep (WB2 frag-block order) ----------------
__global__ __launch_bounds__(256) void prep_and_transpose(const float* __restrict__ x,
                                                          const float* __restrict__ w,
                                                          const float* __restrict__ pw,
                                                          unsigned short* __restrict__ xt,
                                                          unsigned short* __restrict__ WB,
                                                          unsigned short* __restrict__ PWs,
                                                          unsigned short* __restrict__ zerop) {
  __shared__ float tile[32][33];
  int bid = blockIdx.x;
  if (bid < 4096) {
    int b = bid >> 10;
    int rest = bid & 1023;
    int hw0 = (rest & 127) * 32;
    int c0 = ((rest >> 7) & 7) * 32;
    int tx = threadIdx.x & 31, ty = threadIdx.x >> 5;
    for (int i = ty; i < 32; i += 8)
      tile[i][tx] = x[(size_t)(b * CIN + c0 + i) * HWS + hw0 + tx];
    __syncthreads();
    for (int r = ty; r < 32; r += 8)
      xt[(size_t)(b * HWS + hw0 + r) * CIN + c0 + tx] = f2bf(tile[tx][r]);
  } else {
    int idx = (bid - 4096) * 256 + threadIdx.x;
    if (idx < 512)
      *(uint4*)(zerop + idx * 8) = make_uint4(0, 0, 0, 0);
    if (idx < KTOT * COUT) {
      // WB2[t][j][quad][row][8]: f = (((t*16+j)*4+quad)*16+row)*8+e
      int f = idx;
      int e = f & 7;
      int row = (f >> 3) & 15;
      int quad = (f >> 7) & 3;
      int j = (f >> 9) & 15;
      int t = f >> 13;                 // 0..71
      int kk = t * 32 + quad * 8 + e;
      int o = j * 16 + row;
      int k = kk >> 8, c = kk & 255;
      WB[f] = f2bf(w[o * KTOT + c * 9 + k]);
    } else {
      int f2 = idx - KTOT * COUT;   // < 2304*32
      int t_ = f2 & 7;
      int rest = f2 >> 3;
      int j = rest & 31;
      int kk = (rest >> 5) * 8 + t_;
      int k = kk >> 8, c = kk & 255;
      float v = (j < 27) ? pw[j * KTOT + c * 9 + k] : 0.0f;
      PWs[f2] = f2bf(v);
    }
  }
}

// ---------------- K1: offset conv, split-K, BM=64 ----------------
__global__ __launch_bounds__(256) void offset_conv_sk(const unsigned short* __restrict__ xt,
                                                      const unsigned short* __restrict__ PWs,
                                                      const unsigned short* __restrict__ zerop,
                                                      float* __restrict__ Pbuf) {
  __shared__ unsigned short Al[64 * 32];   // 4 KB
  __shared__ unsigned short Bl[1024];      // 2 KB
  int tid = threadIdx.x;
  int lane = tid & 63, wv = tid >> 6;
  int mt = (blockIdx.x & 7) * 32 + (blockIdx.x >> 3);   // XCD swizzle
  int m0 = mt * 64;
  int s = blockIdx.y;
  int b = m0 >> 12;
  int hw0 = m0 & 4095;
  f32x4 acc[2] = {};

  for (int tt = 0; tt < 72 / SPLITK; ++tt) {
    int t = s * (72 / SPLITK) + tt;
    int k = t >> 3, c0 = (t & 7) * 32;
    int dyk = k / 3 - 1;
    int dxk = k % 3 - 1;
    __syncthreads();
    if (tid < 128)
      gload_lds16(PWs + (size_t)t * 1024 + tid * 8, &Bl[tid * 8]);
    {
      int r = tid >> 2;
      int hw = hw0 + r;
      int h = hw >> 6, wwp = hw & 63;
      int y = h + dyk, xx = wwp + dxk;
      bool valid = ((unsigned)y < 64u) && ((unsigned)xx < 64u);
      const unsigned short* src = valid
          ? xt + ((size_t)((b << 12) + (y << 6) + xx) << 8) + c0 + (tid & 3) * 8
          : zerop;
      gload_lds16(src, &Al[tid * 8]);
    }
    __syncthreads();
    int row = lane & 15, quad = lane >> 4;
    bf16x8 af = *(const bf16x8*)&Al[(wv * 16 + row) * 32 + quad * 8];
    for (int j = 0; j < 2; ++j) {
      bf16x8 bfr = *(const bf16x8*)&Bl[(quad * 32 + j * 16 + row) * 8];
      acc[j] = __builtin_amdgcn_mfma_f32_16x16x32_bf16(af, bfr, acc[j], 0, 0, 0);
    }
  }

  int row = lane & 15, quad = lane >> 4;
  for (int j = 0; j < 2; ++j) {
    int n = j * 16 + row;
    for (int r_ = 0; r_ < 4; ++r_) {
      int m = m0 + wv * 16 + quad * 4 + r_;
      Pbuf[((size_t)s * MTOT + m) * 32 + n] = acc[j][r_];
    }
  }
}

// ---------------- K2: index prep — reduce Pbuf, compute corner idx + weights ----------------
__global__ __launch_bounds__(256) void index_prep(const float* __restrict__ Pbuf,
                                                  const float* __restrict__ p_bias,
                                                  int4* __restrict__ DIW) {
  int gid = blockIdx.x * 256 + threadIdx.x;   // 0..147455 == 16384*9
  int m = gid / 9;
  int k = gid - m * 9;

  float dy = p_bias[2 * k];
  float dx = p_bias[2 * k + 1];
  float mv = p_bias[18 + k];
#pragma unroll
  for (int s = 0; s < SPLITK; ++s) {
    const float* p = Pbuf + ((size_t)s * MTOT + m) * 32;
    dy += p[2 * k];
    dx += p[2 * k + 1];
    mv += p[18 + k];
  }
  float mk = 1.0f / (1.0f + __expf(-mv));

  int hw = m & 4095, h = hw >> 6, ww = hw & 63;
  float py = (float)(h - 1 + k / 3) + dy;
  float px = (float)(ww - 1 + k % 3) + dx;
  float y0f = floorf(py), x0f = floorf(px);
  float ay = py - y0f, ax = px - x0f;
  int y0 = (int)y0f, x0 = (int)x0f;

  float w00 = (1.f - ay) * (1.f - ax) * mk;
  float w01 = (1.f - ay) * ax * mk;
  float w10 = ay * (1.f - ax) * mk;
  float w11 = ay * ax * mk;

  float vy0 = ((unsigned)y0 < 64u) ? 1.f : 0.f;
  float vy1 = ((unsigned)(y0 + 1) < 64u) ? 1.f : 0.f;
  float vx0 = ((unsigned)x0 < 64u) ? 1.f : 0.f;
  float vx1 = ((unsigned)(x0 + 1) < 64u) ? 1.f : 0.f;
  w00 *= vy0 * vx0; w01 *= vy0 * vx1; w10 *= vy1 * vx0; w11 *= vy1 * vx1;

  int yc0 = min(max(y0, 0), 63), yc1 = min(max(y0 + 1, 0), 63);
  int xc0 = min(max(x0, 0), 63), xc1 = min(max(x0 + 1, 0), 63);

  DIW[(size_t)gid * 2] = make_int4((yc0 * 64 + xc0) * 256, (yc0 * 64 + xc1) * 256,
                                   (yc1 * 64 + xc0) * 256, (yc1 * 64 + xc1) * 256);
  float4 w4 = make_float4(w00, w01, w10, w11);
  ((float4*)DIW)[(size_t)gid * 2 + 1] = w4;
}

// ---------------- K3: fused sample + GEMM — barrier-free, lane-aligned ----------------
// 256 thr / 4 waves, wave = 16 rows x 256 cols. Lane l: row = l&15,
// k-chunk = (l>>4)*8. A-frag produced in-register by bilin8r. 72 k-tiles,
// zero barriers in the loop; all loads compiler-tracked.
__device__ __forceinline__ bf16x8 bilin8r(const uint4 c00, const uint4 c01,
                                          const uint4 c10, const uint4 c11,
                                          const float4 w4) {
  uint4 o;
  float v0, v1;
  v0 = w4.x * bflo(c00.x) + w4.y * bflo(c01.x) + w4.z * bflo(c10.x) + w4.w * bflo(c11.x);
  v1 = w4.x * bfhi(c00.x) + w4.y * bfhi(c01.x) + w4.z * bfhi(c10.x) + w4.w * bfhi(c11.x);
  o.x = (unsigned)f2bf(v0) | ((unsigned)f2bf(v1) << 16);
  v0 = w4.x * bflo(c00.y) + w4.y * bflo(c01.y) + w4.z * bflo(c10.y) + w4.w * bflo(c11.y);
  v1 = w4.x * bfhi(c00.y) + w4.y * bfhi(c01.y) + w4.z * bfhi(c10.y) + w4.w * bfhi(c11.y);
  o.y = (unsigned)f2bf(v0) | ((unsigned)f2bf(v1) << 16);
  v0 = w4.x * bflo(c00.z) + w4.y * bflo(c01.z) + w4.z * bflo(c10.z) + w4.w * bflo(c11.z);
  v1 = w4.x * bfhi(c00.z) + w4.y * bfhi(c01.z) + w4.z * bfhi(c10.z) + w4.w * bfhi(c11.z);
  o.z = (unsigned)f2bf(v0) | ((unsigned)f2bf(v1) << 16);
  v0 = w4.x * bflo(c00.w) + w4.y * bflo(c01.w) + w4.z * bflo(c10.w) + w4.w * bflo(c11.w);
  v1 = w4.x * bfhi(c00.w) + w4.y * bfhi(c01.w) + w4.z * bfhi(c10.w) + w4.w * bfhi(c11.w);
  o.w = (unsigned)f2bf(v0) | ((unsigned)f2bf(v1) << 16);
  return *(bf16x8*)&o;
}

#define MFMA16J(AC, BC)                                                                   \
  acc[0]  = __builtin_amdgcn_mfma_f32_16x16x32_bf16(AC, BC##0,  acc[0],  0, 0, 0);        \
  acc[1]  = __builtin_amdgcn_mfma_f32_16x16x32_bf16(AC, BC##1,  acc[1],  0, 0, 0);        \
  acc[2]  = __builtin_amdgcn_mfma_f32_16x16x32_bf16(AC, BC##2,  acc[2],  0, 0, 0);        \
  acc[3]  = __builtin_amdgcn_mfma_f32_16x16x32_bf16(AC, BC##3,  acc[3],  0, 0, 0);        \
  acc[4]  = __builtin_amdgcn_mfma_f32_16x16x32_bf16(AC, BC##4,  acc[4],  0, 0, 0);        \
  acc[5]  = __builtin_amdgcn_mfma_f32_16x16x32_bf16(AC, BC##5,  acc[5],  0, 0, 0);        \
  acc[6]  = __builtin_amdgcn_mfma_f32_16x16x32_bf16(AC, BC##6,  acc[6],  0, 0, 0);        \
  acc[7]  = __builtin_amdgcn_mfma_f32_16x16x32_bf16(AC, BC##7,  acc[7],  0, 0, 0);        \
  acc[8]  = __builtin_amdgcn_mfma_f32_16x16x32_bf16(AC, BC##8,  acc[8],  0, 0, 0);        \
  acc[9]  = __builtin_amdgcn_mfma_f32_16x16x32_bf16(AC, BC##9,  acc[9],  0, 0, 0);        \
  acc[10] = __builtin_amdgcn_mfma_f32_16x16x32_bf16(AC, BC##10, acc[10], 0, 0, 0);        \
  acc[11] = __builtin_amdgcn_mfma_f32_16x16x32_bf16(AC, BC##11, acc[11], 0, 0, 0);        \
  acc[12] = __builtin_amdgcn_mfma_f32_16x16x32_bf16(AC, BC##12, acc[12], 0, 0, 0);        \
  acc[13] = __builtin_amdgcn_mfma_f32_16x16x32_bf16(AC, BC##13, acc[13], 0, 0, 0);        \
  acc[14] = __builtin_amdgcn_mfma_f32_16x16x32_bf16(AC, BC##14, acc[14], 0, 0, 0);        \
  acc[15] = __builtin_amdgcn_mfma_f32_16x16x32_bf16(AC, BC##15, acc[15], 0, 0, 0);

#define LOADB16(BI, PTR)                                                                  \
  {                                                                                       \
    const unsigned short* b_ = (PTR);                                                     \
    BI##0  = *(const bf16x8*)(b_);                                                        \
    BI##1  = *(const bf16x8*)(b_ + 512);                                                  \
    BI##2  = *(const bf16x8*)(b_ + 1024);                                                 \
    BI##3  = *(const bf16x8*)(b_ + 1536);                                                 \
    BI##4  = *(const bf16x8*)(b_ + 2048);                                                 \
    BI##5  = *(const bf16x8*)(b_ + 2560);                                                 \
    BI##6  = *(const bf16x8*)(b_ + 3072);                                                 \
    BI##7  = *(const bf16x8*)(b_ + 3584);                                                 \
    BI##8  = *(const bf16x8*)(b_ + 4096);                                                 \
    BI##9  = *(const bf16x8*)(b_ + 4608);                                                 \
    BI##10 = *(const bf16x8*)(b_ + 5120);                                                 \
    BI##11 = *(const bf16x8*)(b_ + 5632);                                                 \
    BI##12 = *(const bf16x8*)(b_ + 6144);                                                 \
    BI##13 = *(const bf16x8*)(b_ + 6656);                                                 \
    BI##14 = *(const bf16x8*)(b_ + 7168);                                                 \
    BI##15 = *(const bf16x8*)(b_ + 7680);                                                 \
  }

// Steady k-tile T. BC = B(T) (loaded at T-1). BI receives B(T+1).
// GC = G(T+1) (loaded at T-1). GI receives G(T+2). AC = A(T). AN <- A(T+1).
// Loads first (issue-ahead), then MFMA on period-old B, then bilin on
// period-old G. Compiler inserts counted waits at first use.
#define FITER(T, BC, BI, GC, GI, AC, AN)                                                  \
  {                                                                                       \
    LOADB16(BI, btb + (size_t)((T) + 1) * 8192)                                           \
    if ((((T) + 2) & 7) == 0) dI4 = Tbl[mr][((T) + 2) >> 3][0];                           \
    int cb = (((T) + 2) & 7) * 32 + kq8;                                                  \
    GI##0 = *(const uint4*)(xtb + dI4.x + cb);                                            \
    GI##1 = *(const uint4*)(xtb + dI4.y + cb);                                            \
    GI##2 = *(const uint4*)(xtb + dI4.z + cb);                                            \
    GI##3 = *(const uint4*)(xtb + dI4.w + cb);                                            \
    if ((((T) + 1) & 7) == 0) dW4 = *(float4*)&Tbl[mr][((T) + 1) >> 3][1];                \
    MFMA16J(AC, BC)                                                                       \
    AN = bilin8r(GC##0, GC##1, GC##2, GC##3, dW4);                                        \
  }

__global__ __launch_bounds__(256, 1) void fused_gemm(const unsigned short* __restrict__ xt,
                                                     const int4* __restrict__ DIW,
                                                     const unsigned short* __restrict__ WB,
                                                     const float* __restrict__ bias,
                                                     float* __restrict__ out) {
  __shared__ int4 Tbl[64][9][2];             // 18,432 B [r][tap]{dI, dW}

  int tid = threadIdx.x;
  int lane = tid & 63, wv = tid >> 6;        // 4 waves
  int mt = (blockIdx.x & 7) * 32 + (blockIdx.x >> 3);   // XCD-chunked swizzle
  int mb = mt * 64;
  int b = mb >> 12;
  const unsigned short* xtb = xt + ((size_t)b << 20);

  // stage index/weight table (1152 int4)
  {
    const int4* src = DIW + (size_t)mb * 18;
    int4* dst = (int4*)Tbl;
    for (int i = tid; i < 1152; i += 256)
      gload_lds16(src + i, dst + i);
  }
  __syncthreads();   // the ONLY barrier

  int row = lane & 15;        // A m-row within wave / C output n-col
  int kq = lane >> 4;         // k-chunk quad
  int kq8 = kq * 8;
  int mr = wv * 16 + row;     // Tbl row for this lane

  int4 dI4 = Tbl[mr][0][0];
  float4 dW4 = *(float4*)&Tbl[mr][0][1];

  const unsigned short* btb = WB + kq * 128 + row * 8;   // + t*8192 + j*512

  f32x4 acc[16] = {};
  bf16x8 bA0, bA1, bA2, bA3, bA4, bA5, bA6, bA7,
         bA8, bA9, bA10, bA11, bA12, bA13, bA14, bA15;
  bf16x8 bB0, bB1, bB2, bB3, bB4, bB5, bB6, bB7,
         bB8, bB9, bB10, bB11, bB12, bB13, bB14, bB15;
  uint4 gA0, gA1, gA2, gA3, gB0, gB1, gB2, gB3;
  bf16x8 afA, afB;

  // ---- prologue: A(0), B(0)->bA, G(1)->gA (all compiler loads) ----
  {
    uint4 p00 = *(const uint4*)(xtb + dI4.x + kq8);
    uint4 p01 = *(const uint4*)(xtb + dI4.y + kq8);
    uint4 p10 = *(const uint4*)(xtb + dI4.z + kq8);
    uint4 p11 = *(const uint4*)(xtb + dI4.w + kq8);
    afA = bilin8r(p00, p01, p10, p11, dW4);
    LOADB16(bA, btb)                         // B(0)
    int cb1 = 32 + kq8;                      // G(1): k-tile 1, tap 0
    gA0 = *(const uint4*)(xtb + dI4.x + cb1);
    gA1 = *(const uint4*)(xtb + dI4.y + cb1);
    gA2 = *(const uint4*)(xtb + dI4.z + cb1);
    gA3 = *(const uint4*)(xtb + dI4.w + cb1);
  }

  // ---- steady loop: k-tiles 0..69 (no barriers) ----
#pragma unroll 1
  for (int t = 0; t < 70; t += 2) {
    FITER(t,     bA, bB, gA, gB, afA, afB)
    FITER(t + 1, bB, bA, gB, gA, afB, afA)
  }

  // ---- peeled t=70: consume bA=B(70) [loaded at t=69], gA=G(71) ----
  {
    LOADB16(bB, btb + (size_t)71 * 8192)
    MFMA16J(afA, bA)
    afB = bilin8r(gA0, gA1, gA2, gA3, dW4);  // dW4 = tap 8 (set at t=63)
  }
  // ---- peeled t=71: consume bB=B(71) ----
  {
    MFMA16J(afB, bB)
  }

  // ---- epilogue: add bias, store NCHW ----
  int hwb = (mb & 4095) + wv * 16 + kq * 4;   // m-base of this lane's 4 output rows
#pragma unroll
  for (int j = 0; j < 16; ++j) {
    int o = j * 16 + row;
    float bo = bias[o];
    float4 v;
    v.x = acc[j][0] + bo;
    v.y = acc[j][1] + bo;
    v.z = acc[j][2] + bo;
    v.w = acc[j][3] + bo;
    *(float4*)(out + (((size_t)(b * COUT + o)) << 12) + hwb) = v;
  }
}

// ---------------- launch ----------------
extern "C" void kernel_launch(void* const* d_in, const int* in_sizes, int n_in,
                              void* d_out, int out_size, void* d_ws, size_t ws_size,
                              hipStream_t stream) {
  const float* x        = (const float*)d_in[0];
  const float* weight   = (const float*)d_in[1];
  const float* bias     = (const float*)d_in[2];
  const float* p_weight = (const float*)d_in[3];
  const float* p_bias   = (const float*)d_in[4];
  float* out = (float*)d_out;
  char* ws = (char*)d_ws;

  // workspace layout (bytes); total ~31 MB
  const size_t OFF_XT   = 0;                          //  8,388,608  bf16 NHWC x
  const size_t OFF_WB   = OFF_XT + 8388608;           //  1,179,648  bf16 WB2
  const size_t OFF_PW   = OFF_WB + 1179648;           //    147,456  bf16
  const size_t OFF_P    = OFF_PW + 147456;            // 16,777,216  fp32 partials
  const size_t OFF_ZP   = OFF_P + 16777216;           //      8,192  zeropage
  const size_t OFF_DIW  = OFF_ZP + 8192;              //  4,718,592  idx/weight table

  unsigned short* xt    = (unsigned short*)(ws + OFF_XT);
  unsigned short* WB    = (unsigned short*)(ws + OFF_WB);
  unsigned short* PWs   = (unsigned short*)(ws + OFF_PW);
  float* Pbuf           = (float*)(ws + OFF_P);
  unsigned short* zerop = (unsigned short*)(ws + OFF_ZP);
  int4* DIW             = (int4*)(ws + OFF_DIW);

  prep_and_transpose<<<4096 + 2592, 256, 0, stream>>>(x, weight, p_weight, xt, WB, PWs, zerop);
  offset_conv_sk<<<dim3(MTOT / 64, SPLITK), 256, 0, stream>>>(xt, PWs, zerop, Pbuf);
  index_prep<<<576, 256, 0, stream>>>(Pbuf, p_bias, DIW);
  fused_gemm<<<256, 256, 0, stream>>>(xt, DIW, WB, bias, out);
}

// Round 14
// 126.969 us; speedup vs baseline: 1.2846x; 1.2846x over previous
//
#include <hip/hip_runtime.h>
#include <stdint.h>

// DCNv2 forward, MI355X — R25: revert fused to R22 (verified best, 130.75us
//  total / fused ~42us) + fuse K2 index_prep into the fused prologue.
//  R23 (lane-aligned + asm ledger) aborted; R24 (same, compiler loads)
//  collapsed to VGPR=160 / 80us — third confirmation that plain loads get
//  sunk. The R22 combo (asm-pinned issue, counted PERIOD-OLD vmcnt, lgkm-
//  only barrier, LDS As dbuf) is the only fast-and-stable schedule found.
//  R25 change: each fused block computes its own 64x9 Tbl (verbatim K2
//  math; blocks own disjoint m) -> kills the K2 dispatch + 9.4MB DIW
//  round trip. Prologue ends in __syncthreads (full vmcnt drain) before
//  any pinned loads => steady ledger unchanged.
//  K0 prep_and_transpose, K1 offset_conv_sk unchanged.

#define CIN 256
#define COUT 256
#define HWS 4096      // H*W
#define MTOT 16384    // B*H*W
#define KTOT 2304     // CIN*9
#define SPLITK 8

typedef __attribute__((ext_vector_type(8))) short bf16x8;
typedef __attribute__((ext_vector_type(4))) float f32x4;

__device__ __forceinline__ unsigned short f2bf(float f) {
  unsigned int u = __float_as_uint(f);
  unsigned int r = (u + 0x7fffu + ((u >> 16) & 1u)) >> 16;
  return (unsigned short)r;
}
__device__ __forceinline__ float bf2f(unsigned short u) {
  return __uint_as_float(((unsigned int)u) << 16);
}
// bf16 pair unpack: 1 VALU each.
__device__ __forceinline__ float bflo(unsigned int u) { return __uint_as_float(u << 16); }
__device__ __forceinline__ float bfhi(unsigned int u) { return __uint_as_float(u & 0xffff0000u); }

__device__ __forceinline__ void gload_lds16(const void* g, void* l) {
  __builtin_amdgcn_global_load_lds((const __attribute__((address_space(1))) void*)g,
                                   (__attribute__((address_space(3))) void*)l, 16, 0, 0);
}

// Issue-pinned loads; completion via manual counted s_waitcnt + sched fence.
#define GLOAD16(D, P) asm volatile("global_load_dwordx4 %0, %1, off" : "=v"(D) : "v"(P))
#define WAITVM(N)                                            \
  {                                                          \
    asm volatile("s_waitcnt vmcnt(" #N ")" ::: "memory");    \
    __builtin_amdgcn_sched_barrier(0);                       \
  }
#define BARRIER_LGKM                                                  \
  { asm volatile("s_waitcnt lgkmcnt(0)\n\ts_barrier" ::: "memory"); }

// As column swizzle: applied identically on write and read (bits 3..5 only,
// so 16B-aligned 8-element runs stay aligned).
#define ASW(c, rr) ((c) ^ (((rr) & 7) << 3))

// ---------------- K0: fused transpose + weight prep (WB2 frag-block order) ----------------
__global__ __launch_bounds__(256) void prep_and_transpose(const float* __restrict__ x,
                                                          const float* __restrict__ w,
                                                          const float* __restrict__ pw,
                                                          unsigned short* __restrict__ xt,
                                                          unsigned short* __restrict__ WB,
                                                          unsigned short* __restrict__ PWs,
                                                          unsigned short* __restrict__ zerop) {
  __shared__ float tile[32][33];
  int bid = blockIdx.x;
  if (bid < 4096) {
    int b = bid >> 10;
    int rest = bid & 1023;
    int hw0 = (rest & 127) * 32;
    int c0 = ((rest >> 7) & 7) * 32;
    int tx = threadIdx.x & 31, ty = threadIdx.x >> 5;
    for (int i = ty; i < 32; i += 8)
      tile[i][tx] = x[(size_t)(b * CIN + c0 + i) * HWS + hw0 + tx];
    __syncthreads();
    for (int r = ty; r < 32; r += 8)
      xt[(size_t)(b * HWS + hw0 + r) * CIN + c0 + tx] = f2bf(tile[tx][r]);
  } else {
    int idx = (bid - 4096) * 256 + threadIdx.x;
    if (idx < 512)
      *(uint4*)(zerop + idx * 8) = make_uint4(0, 0, 0, 0);
    if (idx < KTOT * COUT) {
      // WB2[t][j][quad][row][8]: f = (((t*16+j)*4+quad)*16+row)*8+e
      int f = idx;
      int e = f & 7;
      int row = (f >> 3) & 15;
      int quad = (f >> 7) & 3;
      int j = (f >> 9) & 15;
      int t = f >> 13;                 // 0..71
      int kk = t * 32 + quad * 8 + e;
      int o = j * 16 + row;
      int k = kk >> 8, c = kk & 255;
      WB[f] = f2bf(w[o * KTOT + c * 9 + k]);
    } else {
      int f2 = idx - KTOT * COUT;   // < 2304*32
      int t_ = f2 & 7;
      int rest = f2 >> 3;
      int j = rest & 31;
      int kk = (rest >> 5) * 8 + t_;
      int k = kk >> 8, c = kk & 255;
      float v = (j < 27) ? pw[j * KTOT + c * 9 + k] : 0.0f;
      PWs[f2] = f2bf(v);
    }
  }
}

// ---------------- K1: offset conv, split-K, BM=64 ----------------
__global__ __launch_bounds__(256) void offset_conv_sk(const unsigned short* __restrict__ xt,
                                                      const unsigned short* __restrict__ PWs,
                                                      const unsigned short* __restrict__ zerop,
                                                      float* __restrict__ Pbuf) {
  __shared__ unsigned short Al[64 * 32];   // 4 KB
  __shared__ unsigned short Bl[1024];      // 2 KB
  int tid = threadIdx.x;
  int lane = tid & 63, wv = tid >> 6;
  int mt = (blockIdx.x & 7) * 32 + (blockIdx.x >> 3);   // XCD swizzle
  int m0 = mt * 64;
  int s = blockIdx.y;
  int b = m0 >> 12;
  int hw0 = m0 & 4095;
  f32x4 acc[2] = {};

  for (int tt = 0; tt < 72 / SPLITK; ++tt) {
    int t = s * (72 / SPLITK) + tt;
    int k = t >> 3, c0 = (t & 7) * 32;
    int dyk = k / 3 - 1;
    int dxk = k % 3 - 1;
    __syncthreads();
    if (tid < 128)
      gload_lds16(PWs + (size_t)t * 1024 + tid * 8, &Bl[tid * 8]);
    {
      int r = tid >> 2;
      int hw = hw0 + r;
      int h = hw >> 6, wwp = hw & 63;
      int y = h + dyk, xx = wwp + dxk;
      bool valid = ((unsigned)y < 64u) && ((unsigned)xx < 64u);
      const unsigned short* src = valid
          ? xt + ((size_t)((b << 12) + (y << 6) + xx) << 8) + c0 + (tid & 3) * 8
          : zerop;
      gload_lds16(src, &Al[tid * 8]);
    }
    __syncthreads();
    int row = lane & 15, quad = lane >> 4;
    bf16x8 af = *(const bf16x8*)&Al[(wv * 16 + row) * 32 + quad * 8];
    for (int j = 0; j < 2; ++j) {
      bf16x8 bfr = *(const bf16x8*)&Bl[(quad * 32 + j * 16 + row) * 8];
      acc[j] = __builtin_amdgcn_mfma_f32_16x16x32_bf16(af, bfr, acc[j], 0, 0, 0);
    }
  }

  int row = lane & 15, quad = lane >> 4;
  for (int j = 0; j < 2; ++j) {
    int n = j * 16 + row;
    for (int r_ = 0; r_ < 4; ++r_) {
      int m = m0 + wv * 16 + quad * 4 + r_;
      Pbuf[((size_t)s * MTOT + m) * 32 + n] = acc[j][r_];
    }
  }
}

// ---------------- K3: fused sample + GEMM — R22 pipeline + in-block index prep ----------------
// 512 thr / 8 waves, BM=64, N-split 8 x 32 cols. 36 periods of 2 k-tiles.
// Steady period P: issue B(P+1)x4 [GLOAD16] -> alt set; issue G(P+2)x4
// [GLOAD16, thread covers 8ch/corner]; ds_read A(P); vmcnt(12) -> 16 MFMA
// (B(P), period-old); vmcnt(8) -> bilin8 (G(P+1), period-old) -> As[PAR^1];
// lgkm-only barrier. Prologue computes Tbl (ex-K2) in-block.
__device__ __forceinline__ void bilin8p(const uint4 c00, const uint4 c01,
                                        const uint4 c10, const uint4 c11,
                                        const float4 w4, unsigned short* dst) {
  uint4 o;
  float v0, v1;
  v0 = w4.x * bflo(c00.x) + w4.y * bflo(c01.x) + w4.z * bflo(c10.x) + w4.w * bflo(c11.x);
  v1 = w4.x * bfhi(c00.x) + w4.y * bfhi(c01.x) + w4.z * bfhi(c10.x) + w4.w * bfhi(c11.x);
  o.x = (unsigned)f2bf(v0) | ((unsigned)f2bf(v1) << 16);
  v0 = w4.x * bflo(c00.y) + w4.y * bflo(c01.y) + w4.z * bflo(c10.y) + w4.w * bflo(c11.y);
  v1 = w4.x * bfhi(c00.y) + w4.y * bfhi(c01.y) + w4.z * bfhi(c10.y) + w4.w * bfhi(c11.y);
  o.y = (unsigned)f2bf(v0) | ((unsigned)f2bf(v1) << 16);
  v0 = w4.x * bflo(c00.z) + w4.y * bflo(c01.z) + w4.z * bflo(c10.z) + w4.w * bflo(c11.z);
  v1 = w4.x * bfhi(c00.z) + w4.y * bfhi(c01.z) + w4.z * bfhi(c10.z) + w4.w * bfhi(c11.z);
  o.z = (unsigned)f2bf(v0) | ((unsigned)f2bf(v1) << 16);
  v0 = w4.x * bflo(c00.w) + w4.y * bflo(c01.w) + w4.z * bflo(c10.w) + w4.w * bflo(c11.w);
  v1 = w4.x * bfhi(c00.w) + w4.y * bfhi(c01.w) + w4.z * bfhi(c10.w) + w4.w * bfhi(c11.w);
  o.w = (unsigned)f2bf(v0) | ((unsigned)f2bf(v1) << 16);
  *(uint4*)dst = o;
}

#define MFMA16P(B0, B1, B2, B3)                                                          \
  acc[0][0] = __builtin_amdgcn_mfma_f32_16x16x32_bf16(afr0, B0, acc[0][0], 0, 0, 0);     \
  acc[0][1] = __builtin_amdgcn_mfma_f32_16x16x32_bf16(afr0, B1, acc[0][1], 0, 0, 0);     \
  acc[1][0] = __builtin_amdgcn_mfma_f32_16x16x32_bf16(afr1, B0, acc[1][0], 0, 0, 0);     \
  acc[1][1] = __builtin_amdgcn_mfma_f32_16x16x32_bf16(afr1, B1, acc[1][1], 0, 0, 0);     \
  acc[2][0] = __builtin_amdgcn_mfma_f32_16x16x32_bf16(afr2, B0, acc[2][0], 0, 0, 0);     \
  acc[2][1] = __builtin_amdgcn_mfma_f32_16x16x32_bf16(afr2, B1, acc[2][1], 0, 0, 0);     \
  acc[3][0] = __builtin_amdgcn_mfma_f32_16x16x32_bf16(afr3, B0, acc[3][0], 0, 0, 0);     \
  acc[3][1] = __builtin_amdgcn_mfma_f32_16x16x32_bf16(afr3, B1, acc[3][1], 0, 0, 0);     \
  acc[0][0] = __builtin_amdgcn_mfma_f32_16x16x32_bf16(afr4, B2, acc[0][0], 0, 0, 0);     \
  acc[0][1] = __builtin_amdgcn_mfma_f32_16x16x32_bf16(afr4, B3, acc[0][1], 0, 0, 0);     \
  acc[1][0] = __builtin_amdgcn_mfma_f32_16x16x32_bf16(afr5, B2, acc[1][0], 0, 0, 0);     \
  acc[1][1] = __builtin_amdgcn_mfma_f32_16x16x32_bf16(afr5, B3, acc[1][1], 0, 0, 0);     \
  acc[2][0] = __builtin_amdgcn_mfma_f32_16x16x32_bf16(afr6, B2, acc[2][0], 0, 0, 0);     \
  acc[2][1] = __builtin_amdgcn_mfma_f32_16x16x32_bf16(afr6, B3, acc[2][1], 0, 0, 0);     \
  acc[3][0] = __builtin_amdgcn_mfma_f32_16x16x32_bf16(afr7, B2, acc[3][0], 0, 0, 0);     \
  acc[3][1] = __builtin_amdgcn_mfma_f32_16x16x32_bf16(afr7, B3, acc[3][1], 0, 0, 0);

// Steady period P. GI* receive G(P+2 data); GC* hold G(P+1) (issued at P-1).
// BI* receive B(P+1); BC* hold B(P) (issued at P-1, oldest in flight).
#define FITER_P2(P, PAR, GI0, GI1, GI2, GI3, GC0, GC1, GC2, GC3,                         \
                 BC0, BC1, BC2, BC3, BI0, BI1, BI2, BI3)                                 \
  {                                                                                      \
    const unsigned short* btn = bpb + (size_t)(2 * ((P) + 1)) * 8192;                    \
    GLOAD16(BI0, btn);                                                                   \
    GLOAD16(BI1, btn + 512);                                                             \
    GLOAD16(BI2, btn + 8192);                                                            \
    GLOAD16(BI3, btn + 8192 + 512);                                                      \
    if ((((P) + 2) & 3) == 0) dI4 = Tbl[r][((P) + 2) >> 2][0];                           \
    int cb = ((2 * (P) + 4) & 7) * 32 + qo8;                                             \
    GLOAD16(GI0, xtb + dI4.x + cb);                                                      \
    GLOAD16(GI1, xtb + dI4.y + cb);                                                      \
    GLOAD16(GI2, xtb + dI4.z + cb);                                                      \
    GLOAD16(GI3, xtb + dI4.w + cb);                                                      \
    afr0 = *(const bf16x8*)&As[PAR][row][ASW(quad * 8, row)];                            \
    afr1 = *(const bf16x8*)&As[PAR][16 + row][ASW(quad * 8, row)];                       \
    afr2 = *(const bf16x8*)&As[PAR][32 + row][ASW(quad * 8, row)];                       \
    afr3 = *(const bf16x8*)&As[PAR][48 + row][ASW(quad * 8, row)];                       \
    afr4 = *(const bf16x8*)&As[PAR][row][ASW(32 + quad * 8, row)];                       \
    afr5 = *(const bf16x8*)&As[PAR][16 + row][ASW(32 + quad * 8, row)];                  \
    afr6 = *(const bf16x8*)&As[PAR][32 + row][ASW(32 + quad * 8, row)];                  \
    afr7 = *(const bf16x8*)&As[PAR][48 + row][ASW(32 + quad * 8, row)];                  \
    if ((((P) + 1) & 3) == 0) dW4 = *(float4*)&Tbl[r][((P) + 1) >> 2][1];                \
    WAITVM(12)                                                                           \
    MFMA16P(BC0, BC1, BC2, BC3)                                                          \
    WAITVM(8)                                                                            \
    bilin8p(GC0, GC1, GC2, GC3, dW4, &As[PAR ^ 1][r][ASW(qo8, r)]);                      \
    BARRIER_LGKM                                                                         \
  }

__global__ __launch_bounds__(512, 2) void fused_gemm(const unsigned short* __restrict__ xt,
                                                     const float* __restrict__ Pbuf,
                                                     const float* __restrict__ p_bias,
                                                     const unsigned short* __restrict__ WB,
                                                     const float* __restrict__ bias,
                                                     float* __restrict__ out) {
  __shared__ unsigned short As[2][64][64];   // 32,768 B, XOR-swizzled columns
  __shared__ int4 Tbl[64][9][2];             // 18,432 B [r][tap]{dI, dW}

  int tid = threadIdx.x;
  int lane = tid & 63, wv = tid >> 6;        // 8 waves
  int mt = (blockIdx.x & 7) * 32 + (blockIdx.x >> 3);   // XCD-chunked swizzle
  int mb = mt * 64;
  int b = mb >> 12;
  int hw0 = mb & 4095;
  const unsigned short* xtb = xt + ((size_t)b << 20);

  // ---- in-block index prep (ex-K2): 576 (row, tap) pairs over 512 threads ----
  for (int pr = tid; pr < 576; pr += 512) {
    int lm = pr / 9;
    int k = pr - lm * 9;
    int m = mb + lm;

    float dy = p_bias[2 * k];
    float dx = p_bias[2 * k + 1];
    float mv = p_bias[18 + k];
#pragma unroll
    for (int s = 0; s < SPLITK; ++s) {
      const float* p = Pbuf + ((size_t)s * MTOT + m) * 32;
      dy += p[2 * k];
      dx += p[2 * k + 1];
      mv += p[18 + k];
    }
    float mk = 1.0f / (1.0f + __expf(-mv));

    int hw = m & 4095, h = hw >> 6, ww = hw & 63;
    float py = (float)(h - 1 + k / 3) + dy;
    float px = (float)(ww - 1 + k % 3) + dx;
    float y0f = floorf(py), x0f = floorf(px);
    float ay = py - y0f, ax = px - x0f;
    int y0 = (int)y0f, x0 = (int)x0f;

    float w00 = (1.f - ay) * (1.f - ax) * mk;
    float w01 = (1.f - ay) * ax * mk;
    float w10 = ay * (1.f - ax) * mk;
    float w11 = ay * ax * mk;

    float vy0 = ((unsigned)y0 < 64u) ? 1.f : 0.f;
    float vy1 = ((unsigned)(y0 + 1) < 64u) ? 1.f : 0.f;
    float vx0 = ((unsigned)x0 < 64u) ? 1.f : 0.f;
    float vx1 = ((unsigned)(x0 + 1) < 64u) ? 1.f : 0.f;
    w00 *= vy0 * vx0; w01 *= vy0 * vx1; w10 *= vy1 * vx0; w11 *= vy1 * vx1;

    int yc0 = min(max(y0, 0), 63), yc1 = min(max(y0 + 1, 0), 63);
    int xc0 = min(max(x0, 0), 63), xc1 = min(max(x0 + 1, 0), 63);

    Tbl[lm][k][0] = make_int4((yc0 * 64 + xc0) * 256, (yc0 * 64 + xc1) * 256,
                              (yc1 * 64 + xc0) * 256, (yc1 * 64 + xc1) * 256);
    *(float4*)&Tbl[lm][k][1] = make_float4(w00, w01, w10, w11);
  }
  __syncthreads();   // full drain (vmcnt+lgkm) BEFORE any pinned loads

  int r = tid >> 3;         // sampler row 0..63 (8 threads/row)
  int qo8 = (tid & 7) * 8;  // sampler channel sub-block (8 ch, 16 B)

  int4 dI4 = Tbl[r][0][0];
  float4 dW4 = *(float4*)&Tbl[r][0][1];

  int row = lane & 15, quad = lane >> 4;
  const unsigned short* bpb = WB + (size_t)(wv * 2) * 512 + quad * 128 + row * 8;

  f32x4 acc[4][2] = {};
  uint4 gA0, gA1, gA2, gA3;            // even-period gather set
  uint4 gB0, gB1, gB2, gB3;            // odd-period gather set
  bf16x8 bA0, bA1, bA2, bA3;           // even-period B set
  bf16x8 bB0, bB1, bB2, bB3;           // odd-period B set
  bf16x8 afr0, afr1, afr2, afr3, afr4, afr5, afr6, afr7;

  // ---- prologue: sample period 0 via compiler loads; pin B(0), G(1) ----
  {
    uint4 p00 = *(const uint4*)(xtb + dI4.x + qo8);
    uint4 p01 = *(const uint4*)(xtb + dI4.y + qo8);
    uint4 p10 = *(const uint4*)(xtb + dI4.z + qo8);
    uint4 p11 = *(const uint4*)(xtb + dI4.w + qo8);
    bilin8p(p00, p01, p10, p11, dW4, &As[0][r][ASW(qo8, r)]);
    // pinned issues, ORDER: B(0) x4 first (oldest), then G(1) x4
    GLOAD16(bA0, bpb);
    GLOAD16(bA1, bpb + 512);
    GLOAD16(bA2, bpb + 8192);
    GLOAD16(bA3, bpb + 8192 + 512);
    int cb1 = 64 + qo8;   // period 1 = tiles 2,3 (ch 64..127), tap 0
    GLOAD16(gA0, xtb + dI4.x + cb1);
    GLOAD16(gA1, xtb + dI4.y + cb1);
    GLOAD16(gA2, xtb + dI4.z + cb1);
    GLOAD16(gA3, xtb + dI4.w + cb1);
  }
  BARRIER_LGKM   // As[0] visible; 8 pinned loads in flight

  // ---- steady loop: periods 0..33 ----
#pragma unroll 1
  for (int p = 0; p < 34; p += 2) {
    FITER_P2(p,     0, gB0, gB1, gB2, gB3, gA0, gA1, gA2, gA3,
                       bA0, bA1, bA2, bA3, bB0, bB1, bB2, bB3)
    FITER_P2(p + 1, 1, gA0, gA1, gA2, gA3, gB0, gB1, gB2, gB3,
                       bB0, bB1, bB2, bB3, bA0, bA1, bA2, bA3)
  }

  // ---- peeled P=34 (PAR=0): BC=bA=B(34), GC=gA=G(35); issue B(35)->bB ----
  {
    const unsigned short* btn = bpb + (size_t)70 * 8192;
    GLOAD16(bB0, btn);
    GLOAD16(bB1, btn + 512);
    GLOAD16(bB2, btn + 8192);
    GLOAD16(bB3, btn + 8192 + 512);
    afr0 = *(const bf16x8*)&As[0][row][ASW(quad * 8, row)];
    afr1 = *(const bf16x8*)&As[0][16 + row][ASW(quad * 8, row)];
    afr2 = *(const bf16x8*)&As[0][32 + row][ASW(quad * 8, row)];
    afr3 = *(const bf16x8*)&As[0][48 + row][ASW(quad * 8, row)];
    afr4 = *(const bf16x8*)&As[0][row][ASW(32 + quad * 8, row)];
    afr5 = *(const bf16x8*)&As[0][16 + row][ASW(32 + quad * 8, row)];
    afr6 = *(const bf16x8*)&As[0][32 + row][ASW(32 + quad * 8, row)];
    afr7 = *(const bf16x8*)&As[0][48 + row][ASW(32 + quad * 8, row)];
    WAITVM(8)    // drains B(34)
    MFMA16P(bA0, bA1, bA2, bA3)
    WAITVM(4)    // drains G(35)
    bilin8p(gA0, gA1, gA2, gA3, dW4, &As[1][r][ASW(qo8, r)]);   // dW4 = tap 8
    BARRIER_LGKM
  }
  // ---- peeled P=35 (PAR=1): BC=bB=B(35); no bilin ----
  {
    afr0 = *(const bf16x8*)&As[1][row][ASW(quad * 8, row)];
    afr1 = *(const bf16x8*)&As[1][16 + row][ASW(quad * 8, row)];
    afr2 = *(const bf16x8*)&As[1][32 + row][ASW(quad * 8, row)];
    afr3 = *(const bf16x8*)&As[1][48 + row][ASW(quad * 8, row)];
    afr4 = *(const bf16x8*)&As[1][row][ASW(32 + quad * 8, row)];
    afr5 = *(const bf16x8*)&As[1][16 + row][ASW(32 + quad * 8, row)];
    afr6 = *(const bf16x8*)&As[1][32 + row][ASW(32 + quad * 8, row)];
    afr7 = *(const bf16x8*)&As[1][48 + row][ASW(32 + quad * 8, row)];
    WAITVM(0)
    MFMA16P(bB0, bB1, bB2, bB3)
  }

  // ---- epilogue: add bias, store NCHW ----
#pragma unroll
  for (int j = 0; j < 2; ++j) {
    int o = wv * 32 + j * 16 + row;
    float bo = bias[o];
#pragma unroll
    for (int i = 0; i < 4; ++i) {
      int hw = hw0 + i * 16 + quad * 4;
      float4 v;
      v.x = acc[i][j][0] + bo;
      v.y = acc[i][j][1] + bo;
      v.z = acc[i][j][2] + bo;
      v.w = acc[i][j][3] + bo;
      *(float4*)(out + (((size_t)(b * COUT + o)) << 12) + hw) = v;
    }
  }
}

// ---------------- launch ----------------
extern "C" void kernel_launch(void* const* d_in, const int* in_sizes, int n_in,
                              void* d_out, int out_size, void* d_ws, size_t ws_size,
                              hipStream_t stream) {
  const float* x        = (const float*)d_in[0];
  const float* weight   = (const float*)d_in[1];
  const float* bias     = (const float*)d_in[2];
  const float* p_weight = (const float*)d_in[3];
  const float* p_bias   = (const float*)d_in[4];
  float* out = (float*)d_out;
  char* ws = (char*)d_ws;

  // workspace layout (bytes); total ~26 MB
  const size_t OFF_XT   = 0;                          //  8,388,608  bf16 NHWC x
  const size_t OFF_WB   = OFF_XT + 8388608;           //  1,179,648  bf16 WB2
  const size_t OFF_PW   = OFF_WB + 1179648;           //    147,456  bf16
  const size_t OFF_P    = OFF_PW + 147456;            // 16,777,216  fp32 partials
  const size_t OFF_ZP   = OFF_P + 16777216;           //      8,192  zeropage

  unsigned short* xt    = (unsigned short*)(ws + OFF_XT);
  unsigned short* WB    = (unsigned short*)(ws + OFF_WB);
  unsigned short* PWs   = (unsigned short*)(ws + OFF_PW);
  float* Pbuf           = (float*)(ws + OFF_P);
  unsigned short* zerop = (unsigned short*)(ws + OFF_ZP);

  prep_and_transpose<<<4096 + 2592, 256, 0, stream>>>(x, weight, p_weight, xt, WB, PWs, zerop);
  offset_conv_sk<<<dim3(MTOT / 64, SPLITK), 256, 0, stream>>>(xt, PWs, zerop, Pbuf);
  fused_gemm<<<256, 512, 0, stream>>>(xt, Pbuf, p_bias, WB, bias, out);
}

// Round 15
// 125.680 us; speedup vs baseline: 1.2978x; 1.0103x over previous
//
#include <hip/hip_runtime.h>
#include <stdint.h>

// DCNv2 forward, MI355X — R26: fuse K1 offset conv into the fused prologue.
//  R25 (126.97us, best): K2 fused, all kernels < 46us; K0+K1+gaps ~80us now
//  dominate. K1 has the known-bad per-tile drain-barrier structure (2048
//  blocks x 9 tiles of __syncthreads+global_load_lds) + 31MB Pbuf traffic.
//  R26: offset conv needs NO bilinear — its A-frag is a lane-aligned 16B
//  load from xt (8 contig channels of a tap-shifted row). Each fused block
//  computes its own 64 rows in the prologue: wave w covers k-tiles 9w..9w+8
//  barrier-free (reg accumulation), partials -> LDS Ptl[8][64][32], one
//  reduction, then the verified index-prep math reads LDS. Identical math
//  to K1 (same PWs layout/gathers/C-map); R22-verified steady loop
//  byte-identical from the first __syncthreads onward. 2 dispatches total;
//  Pbuf eliminated. K0 prep_and_transpose unchanged.

#define CIN 256
#define COUT 256
#define HWS 4096      // H*W
#define MTOT 16384    // B*H*W
#define KTOT 2304     // CIN*9
#define SPLITK 8

typedef __attribute__((ext_vector_type(8))) short bf16x8;
typedef __attribute__((ext_vector_type(4))) float f32x4;

__device__ __forceinline__ unsigned short f2bf(float f) {
  unsigned int u = __float_as_uint(f);
  unsigned int r = (u + 0x7fffu + ((u >> 16) & 1u)) >> 16;
  return (unsigned short)r;
}
__device__ __forceinline__ float bf2f(unsigned short u) {
  return __uint_as_float(((unsigned int)u) << 16);
}
// bf16 pair unpack: 1 VALU each.
__device__ __forceinline__ float bflo(unsigned int u) { return __uint_as_float(u << 16); }
__device__ __forceinline__ float bfhi(unsigned int u) { return __uint_as_float(u & 0xffff0000u); }

__device__ __forceinline__ void gload_lds16(const void* g, void* l) {
  __builtin_amdgcn_global_load_lds((const __attribute__((address_space(1))) void*)g,
                                   (__attribute__((address_space(3))) void*)l, 16, 0, 0);
}

// Issue-pinned loads; completion via manual counted s_waitcnt + sched fence.
#define GLOAD16(D, P) asm volatile("global_load_dwordx4 %0, %1, off" : "=v"(D) : "v"(P))
#define WAITVM(N)                                            \
  {                                                          \
    asm volatile("s_waitcnt vmcnt(" #N ")" ::: "memory");    \
    __builtin_amdgcn_sched_barrier(0);                       \
  }
#define BARRIER_LGKM                                                  \
  { asm volatile("s_waitcnt lgkmcnt(0)\n\ts_barrier" ::: "memory"); }

// As column swizzle: applied identically on write and read (bits 3..5 only,
// so 16B-aligned 8-element runs stay aligned).
#define ASW(c, rr) ((c) ^ (((rr) & 7) << 3))

// ---------------- K0: fused transpose + weight prep (WB2 frag-block order) ----------------
__global__ __launch_bounds__(256) void prep_and_transpose(const float* __restrict__ x,
                                                          const float* __restrict__ w,
                                                          const float* __restrict__ pw,
                                                          unsigned short* __restrict__ xt,
                                                          unsigned short* __restrict__ WB,
                                                          unsigned short* __restrict__ PWs,
                                                          unsigned short* __restrict__ zerop) {
  __shared__ float tile[32][33];
  int bid = blockIdx.x;
  if (bid < 4096) {
    int b = bid >> 10;
    int rest = bid & 1023;
    int hw0 = (rest & 127) * 32;
    int c0 = ((rest >> 7) & 7) * 32;
    int tx = threadIdx.x & 31, ty = threadIdx.x >> 5;
    for (int i = ty; i < 32; i += 8)
      tile[i][tx] = x[(size_t)(b * CIN + c0 + i) * HWS + hw0 + tx];
    __syncthreads();
    for (int r = ty; r < 32; r += 8)
      xt[(size_t)(b * HWS + hw0 + r) * CIN + c0 + tx] = f2bf(tile[tx][r]);
  } else {
    int idx = (bid - 4096) * 256 + threadIdx.x;
    if (idx < 512)
      *(uint4*)(zerop + idx * 8) = make_uint4(0, 0, 0, 0);
    if (idx < KTOT * COUT) {
      // WB2[t][j][quad][row][8]: f = (((t*16+j)*4+quad)*16+row)*8+e
      int f = idx;
      int e = f & 7;
      int row = (f >> 3) & 15;
      int quad = (f >> 7) & 3;
      int j = (f >> 9) & 15;
      int t = f >> 13;                 // 0..71
      int kk = t * 32 + quad * 8 + e;
      int o = j * 16 + row;
      int k = kk >> 8, c = kk & 255;
      WB[f] = f2bf(w[o * KTOT + c * 9 + k]);
    } else {
      int f2 = idx - KTOT * COUT;   // < 2304*32
      int t_ = f2 & 7;
      int rest = f2 >> 3;
      int j = rest & 31;
      int kk = (rest >> 5) * 8 + t_;
      int k = kk >> 8, c = kk & 255;
      float v = (j < 27) ? pw[j * KTOT + c * 9 + k] : 0.0f;
      PWs[f2] = f2bf(v);
    }
  }
}

// ---------------- K3: fused offset-conv + index-prep + sample + GEMM ----------------
// 512 thr / 8 waves, BM=64, N-split 8 x 32 cols. 36 periods of 2 k-tiles.
// Prologue: (a) offset conv — wave w covers k-tiles 9w..9w+8, reg-accum,
// partials -> Ptl; (b) 8-wave reduction; (c) index-prep math -> Tbl;
// (d) sample period 0 -> As[0]; (e) pin B(0), G(1). Steady loop = R22:
// per period issue B(P+1)x4 + G(P+2)x4 [GLOAD16]; ds_read A(P); vmcnt(12)
// -> 16 MFMA (B period-old); vmcnt(8) -> bilin8 (G period-old); lgkm-only
// barrier.
__device__ __forceinline__ void bilin8p(const uint4 c00, const uint4 c01,
                                        const uint4 c10, const uint4 c11,
                                        const float4 w4, unsigned short* dst) {
  uint4 o;
  float v0, v1;
  v0 = w4.x * bflo(c00.x) + w4.y * bflo(c01.x) + w4.z * bflo(c10.x) + w4.w * bflo(c11.x);
  v1 = w4.x * bfhi(c00.x) + w4.y * bfhi(c01.x) + w4.z * bfhi(c10.x) + w4.w * bfhi(c11.x);
  o.x = (unsigned)f2bf(v0) | ((unsigned)f2bf(v1) << 16);
  v0 = w4.x * bflo(c00.y) + w4.y * bflo(c01.y) + w4.z * bflo(c10.y) + w4.w * bflo(c11.y);
  v1 = w4.x * bfhi(c00.y) + w4.y * bfhi(c01.y) + w4.z * bfhi(c10.y) + w4.w * bfhi(c11.y);
  o.y = (unsigned)f2bf(v0) | ((unsigned)f2bf(v1) << 16);
  v0 = w4.x * bflo(c00.z) + w4.y * bflo(c01.z) + w4.z * bflo(c10.z) + w4.w * bflo(c11.z);
  v1 = w4.x * bfhi(c00.z) + w4.y * bfhi(c01.z) + w4.z * bfhi(c10.z) + w4.w * bfhi(c11.z);
  o.z = (unsigned)f2bf(v0) | ((unsigned)f2bf(v1) << 16);
  v0 = w4.x * bflo(c00.w) + w4.y * bflo(c01.w) + w4.z * bflo(c10.w) + w4.w * bflo(c11.w);
  v1 = w4.x * bfhi(c00.w) + w4.y * bfhi(c01.w) + w4.z * bfhi(c10.w) + w4.w * bfhi(c11.w);
  o.w = (unsigned)f2bf(v0) | ((unsigned)f2bf(v1) << 16);
  *(uint4*)dst = o;
}

#define MFMA16P(B0, B1, B2, B3)                                                          \
  acc[0][0] = __builtin_amdgcn_mfma_f32_16x16x32_bf16(afr0, B0, acc[0][0], 0, 0, 0);     \
  acc[0][1] = __builtin_amdgcn_mfma_f32_16x16x32_bf16(afr0, B1, acc[0][1], 0, 0, 0);     \
  acc[1][0] = __builtin_amdgcn_mfma_f32_16x16x32_bf16(afr1, B0, acc[1][0], 0, 0, 0);     \
  acc[1][1] = __builtin_amdgcn_mfma_f32_16x16x32_bf16(afr1, B1, acc[1][1], 0, 0, 0);     \
  acc[2][0] = __builtin_amdgcn_mfma_f32_16x16x32_bf16(afr2, B0, acc[2][0], 0, 0, 0);     \
  acc[2][1] = __builtin_amdgcn_mfma_f32_16x16x32_bf16(afr2, B1, acc[2][1], 0, 0, 0);     \
  acc[3][0] = __builtin_amdgcn_mfma_f32_16x16x32_bf16(afr3, B0, acc[3][0], 0, 0, 0);     \
  acc[3][1] = __builtin_amdgcn_mfma_f32_16x16x32_bf16(afr3, B1, acc[3][1], 0, 0, 0);     \
  acc[0][0] = __builtin_amdgcn_mfma_f32_16x16x32_bf16(afr4, B2, acc[0][0], 0, 0, 0);     \
  acc[0][1] = __builtin_amdgcn_mfma_f32_16x16x32_bf16(afr4, B3, acc[0][1], 0, 0, 0);     \
  acc[1][0] = __builtin_amdgcn_mfma_f32_16x16x32_bf16(afr5, B2, acc[1][0], 0, 0, 0);     \
  acc[1][1] = __builtin_amdgcn_mfma_f32_16x16x32_bf16(afr5, B3, acc[1][1], 0, 0, 0);     \
  acc[2][0] = __builtin_amdgcn_mfma_f32_16x16x32_bf16(afr6, B2, acc[2][0], 0, 0, 0);     \
  acc[2][1] = __builtin_amdgcn_mfma_f32_16x16x32_bf16(afr6, B3, acc[2][1], 0, 0, 0);     \
  acc[3][0] = __builtin_amdgcn_mfma_f32_16x16x32_bf16(afr7, B2, acc[3][0], 0, 0, 0);     \
  acc[3][1] = __builtin_amdgcn_mfma_f32_16x16x32_bf16(afr7, B3, acc[3][1], 0, 0, 0);

// Steady period P. GI* receive G(P+2 data); GC* hold G(P+1) (issued at P-1).
// BI* receive B(P+1); BC* hold B(P) (issued at P-1, oldest in flight).
#define FITER_P2(P, PAR, GI0, GI1, GI2, GI3, GC0, GC1, GC2, GC3,                         \
                 BC0, BC1, BC2, BC3, BI0, BI1, BI2, BI3)                                 \
  {                                                                                      \
    const unsigned short* btn = bpb + (size_t)(2 * ((P) + 1)) * 8192;                    \
    GLOAD16(BI0, btn);                                                                   \
    GLOAD16(BI1, btn + 512);                                                             \
    GLOAD16(BI2, btn + 8192);                                                            \
    GLOAD16(BI3, btn + 8192 + 512);                                                      \
    if ((((P) + 2) & 3) == 0) dI4 = Tbl[r][((P) + 2) >> 2][0];                           \
    int cb = ((2 * (P) + 4) & 7) * 32 + qo8;                                             \
    GLOAD16(GI0, xtb + dI4.x + cb);                                                      \
    GLOAD16(GI1, xtb + dI4.y + cb);                                                      \
    GLOAD16(GI2, xtb + dI4.z + cb);                                                      \
    GLOAD16(GI3, xtb + dI4.w + cb);                                                      \
    afr0 = *(const bf16x8*)&As[PAR][row][ASW(quad * 8, row)];                            \
    afr1 = *(const bf16x8*)&As[PAR][16 + row][ASW(quad * 8, row)];                       \
    afr2 = *(const bf16x8*)&As[PAR][32 + row][ASW(quad * 8, row)];                       \
    afr3 = *(const bf16x8*)&As[PAR][48 + row][ASW(quad * 8, row)];                       \
    afr4 = *(const bf16x8*)&As[PAR][row][ASW(32 + quad * 8, row)];                       \
    afr5 = *(const bf16x8*)&As[PAR][16 + row][ASW(32 + quad * 8, row)];                  \
    afr6 = *(const bf16x8*)&As[PAR][32 + row][ASW(32 + quad * 8, row)];                  \
    afr7 = *(const bf16x8*)&As[PAR][48 + row][ASW(32 + quad * 8, row)];                  \
    if ((((P) + 1) & 3) == 0) dW4 = *(float4*)&Tbl[r][((P) + 1) >> 2][1];                \
    WAITVM(12)                                                                           \
    MFMA16P(BC0, BC1, BC2, BC3)                                                          \
    WAITVM(8)                                                                            \
    bilin8p(GC0, GC1, GC2, GC3, dW4, &As[PAR ^ 1][r][ASW(qo8, r)]);                      \
    BARRIER_LGKM                                                                         \
  }

__global__ __launch_bounds__(512, 2) void fused_gemm(const unsigned short* __restrict__ xt,
                                                     const unsigned short* __restrict__ PWs,
                                                     const float* __restrict__ p_bias,
                                                     const unsigned short* __restrict__ WB,
                                                     const float* __restrict__ bias,
                                                     float* __restrict__ out) {
  __shared__ unsigned short As[2][64][64];   // 16,384 B, XOR-swizzled columns
  __shared__ int4 Tbl[64][9][2];             // 18,432 B [r][tap]{dI, dW}
  __shared__ float Ptl[8][64][32];           // 65,536 B offset-conv partials

  int tid = threadIdx.x;
  int lane = tid & 63, wv = tid >> 6;        // 8 waves
  int row = lane & 15, quad = lane >> 4;
  int mt = (blockIdx.x & 7) * 32 + (blockIdx.x >> 3);   // XCD-chunked swizzle
  int mb = mt * 64;
  int b = mb >> 12;
  int hw0 = mb & 4095;
  const unsigned short* xtb = xt + ((size_t)b << 20);

  // ---- (a) offset conv (ex-K1): wave wv covers k-tiles 9wv..9wv+8 ----
  {
    f32x4 aco[4][2] = {};
    for (int tt = 0; tt < 9; ++tt) {
      int t = wv * 9 + tt;
      int k = t >> 3, c0 = (t & 7) * 32;
      int dyk = k / 3 - 1, dxk = k % 3 - 1;
      const unsigned short* pb = PWs + (size_t)t * 1024 + (quad * 32 + row) * 8;
      bf16x8 ob0 = *(const bf16x8*)pb;           // j=0
      bf16x8 ob1 = *(const bf16x8*)(pb + 128);   // j=1 (+16 rows * 8)
#pragma unroll
      for (int rs = 0; rs < 4; ++rs) {
        int hw = hw0 + rs * 16 + row;
        int h = hw >> 6, wq = hw & 63;
        int y = h + dyk, xx = wq + dxk;
        bf16x8 oa = {};
        if (((unsigned)y < 64u) && ((unsigned)xx < 64u))
          oa = *(const bf16x8*)(xtb + (size_t)(((y << 6) + xx) << 8) + c0 + quad * 8);
        aco[rs][0] = __builtin_amdgcn_mfma_f32_16x16x32_bf16(oa, ob0, aco[rs][0], 0, 0, 0);
        aco[rs][1] = __builtin_amdgcn_mfma_f32_16x16x32_bf16(oa, ob1, aco[rs][1], 0, 0, 0);
      }
    }
#pragma unroll
    for (int rs = 0; rs < 4; ++rs)
#pragma unroll
      for (int j = 0; j < 2; ++j)
#pragma unroll
        for (int e = 0; e < 4; ++e)
          Ptl[wv][rs * 16 + quad * 4 + e][j * 16 + row] = aco[rs][j][e];
  }
  __syncthreads();

  // ---- (b) reduce 8 waves' partials into Ptl[0] ----
  for (int i = tid; i < 2048; i += 512) {
    int lm = i >> 5, n = i & 31;
    float s = Ptl[0][lm][n];
#pragma unroll
    for (int w = 1; w < 8; ++w) s += Ptl[w][lm][n];
    Ptl[0][lm][n] = s;
  }
  __syncthreads();

  // ---- (c) index prep (ex-K2): 576 (row, tap) pairs over 512 threads ----
  for (int pr = tid; pr < 576; pr += 512) {
    int lm = pr / 9;
    int k = pr - lm * 9;
    int m = mb + lm;

    float dy = p_bias[2 * k] + Ptl[0][lm][2 * k];
    float dx = p_bias[2 * k + 1] + Ptl[0][lm][2 * k + 1];
    float mv = p_bias[18 + k] + Ptl[0][lm][18 + k];
    float mk = 1.0f / (1.0f + __expf(-mv));

    int hw = m & 4095, h = hw >> 6, ww = hw & 63;
    float py = (float)(h - 1 + k / 3) + dy;
    float px = (float)(ww - 1 + k % 3) + dx;
    float y0f = floorf(py), x0f = floorf(px);
    float ay = py - y0f, ax = px - x0f;
    int y0 = (int)y0f, x0 = (int)x0f;

    float w00 = (1.f - ay) * (1.f - ax) * mk;
    float w01 = (1.f - ay) * ax * mk;
    float w10 = ay * (1.f - ax) * mk;
    float w11 = ay * ax * mk;

    float vy0 = ((unsigned)y0 < 64u) ? 1.f : 0.f;
    float vy1 = ((unsigned)(y0 + 1) < 64u) ? 1.f : 0.f;
    float vx0 = ((unsigned)x0 < 64u) ? 1.f : 0.f;
    float vx1 = ((unsigned)(x0 + 1) < 64u) ? 1.f : 0.f;
    w00 *= vy0 * vx0; w01 *= vy0 * vx1; w10 *= vy1 * vx0; w11 *= vy1 * vx1;

    int yc0 = min(max(y0, 0), 63), yc1 = min(max(y0 + 1, 0), 63);
    int xc0 = min(max(x0, 0), 63), xc1 = min(max(x0 + 1, 0), 63);

    Tbl[lm][k][0] = make_int4((yc0 * 64 + xc0) * 256, (yc0 * 64 + xc1) * 256,
                              (yc1 * 64 + xc0) * 256, (yc1 * 64 + xc1) * 256);
    *(float4*)&Tbl[lm][k][1] = make_float4(w00, w01, w10, w11);
  }
  __syncthreads();   // full drain (vmcnt+lgkm) BEFORE any pinned loads

  int r = tid >> 3;         // sampler row 0..63 (8 threads/row)
  int qo8 = (tid & 7) * 8;  // sampler channel sub-block (8 ch, 16 B)

  int4 dI4 = Tbl[r][0][0];
  float4 dW4 = *(float4*)&Tbl[r][0][1];

  const unsigned short* bpb = WB + (size_t)(wv * 2) * 512 + quad * 128 + row * 8;

  f32x4 acc[4][2] = {};
  uint4 gA0, gA1, gA2, gA3;            // even-period gather set
  uint4 gB0, gB1, gB2, gB3;            // odd-period gather set
  bf16x8 bA0, bA1, bA2, bA3;           // even-period B set
  bf16x8 bB0, bB1, bB2, bB3;           // odd-period B set
  bf16x8 afr0, afr1, afr2, afr3, afr4, afr5, afr6, afr7;

  // ---- prologue: sample period 0 via compiler loads; pin B(0), G(1) ----
  {
    uint4 p00 = *(const uint4*)(xtb + dI4.x + qo8);
    uint4 p01 = *(const uint4*)(xtb + dI4.y + qo8);
    uint4 p10 = *(const uint4*)(xtb + dI4.z + qo8);
    uint4 p11 = *(const uint4*)(xtb + dI4.w + qo8);
    bilin8p(p00, p01, p10, p11, dW4, &As[0][r][ASW(qo8, r)]);
    // pinned issues, ORDER: B(0) x4 first (oldest), then G(1) x4
    GLOAD16(bA0, bpb);
    GLOAD16(bA1, bpb + 512);
    GLOAD16(bA2, bpb + 8192);
    GLOAD16(bA3, bpb + 8192 + 512);
    int cb1 = 64 + qo8;   // period 1 = tiles 2,3 (ch 64..127), tap 0
    GLOAD16(gA0, xtb + dI4.x + cb1);
    GLOAD16(gA1, xtb + dI4.y + cb1);
    GLOAD16(gA2, xtb + dI4.z + cb1);
    GLOAD16(gA3, xtb + dI4.w + cb1);
  }
  BARRIER_LGKM   // As[0] visible; 8 pinned loads in flight

  // ---- steady loop: periods 0..33 ----
#pragma unroll 1
  for (int p = 0; p < 34; p += 2) {
    FITER_P2(p,     0, gB0, gB1, gB2, gB3, gA0, gA1, gA2, gA3,
                       bA0, bA1, bA2, bA3, bB0, bB1, bB2, bB3)
    FITER_P2(p + 1, 1, gA0, gA1, gA2, gA3, gB0, gB1, gB2, gB3,
                       bB0, bB1, bB2, bB3, bA0, bA1, bA2, bA3)
  }

  // ---- peeled P=34 (PAR=0): BC=bA=B(34), GC=gA=G(35); issue B(35)->bB ----
  {
    const unsigned short* btn = bpb + (size_t)70 * 8192;
    GLOAD16(bB0, btn);
    GLOAD16(bB1, btn + 512);
    GLOAD16(bB2, btn + 8192);
    GLOAD16(bB3, btn + 8192 + 512);
    afr0 = *(const bf16x8*)&As[0][row][ASW(quad * 8, row)];
    afr1 = *(const bf16x8*)&As[0][16 + row][ASW(quad * 8, row)];
    afr2 = *(const bf16x8*)&As[0][32 + row][ASW(quad * 8, row)];
    afr3 = *(const bf16x8*)&As[0][48 + row][ASW(quad * 8, row)];
    afr4 = *(const bf16x8*)&As[0][row][ASW(32 + quad * 8, row)];
    afr5 = *(const bf16x8*)&As[0][16 + row][ASW(32 + quad * 8, row)];
    afr6 = *(const bf16x8*)&As[0][32 + row][ASW(32 + quad * 8, row)];
    afr7 = *(const bf16x8*)&As[0][48 + row][ASW(32 + quad * 8, row)];
    WAITVM(8)    // drains B(34)
    MFMA16P(bA0, bA1, bA2, bA3)
    WAITVM(4)    // drains G(35)
    bilin8p(gA0, gA1, gA2, gA3, dW4, &As[1][r][ASW(qo8, r)]);   // dW4 = tap 8
    BARRIER_LGKM
  }
  // ---- peeled P=35 (PAR=1): BC=bB=B(35); no bilin ----
  {
    afr0 = *(const bf16x8*)&As[1][row][ASW(quad * 8, row)];
    afr1 = *(const bf16x8*)&As[1][16 + row][ASW(quad * 8, row)];
    afr2 = *(const bf16x8*)&As[1][32 + row][ASW(quad * 8, row)];
    afr3 = *(const bf16x8*)&As[1][48 + row][ASW(quad * 8, row)];
    afr4 = *(const bf16x8*)&As[1][row][ASW(32 + quad * 8, row)];
    afr5 = *(const bf16x8*)&As[1][16 + row][ASW(32 + quad * 8, row)];
    afr6 = *(const bf16x8*)&As[1][32 + row][ASW(32 + quad * 8, row)];
    afr7 = *(const bf16x8*)&As[1][48 + row][ASW(32 + quad * 8, row)];
    WAITVM(0)
    MFMA16P(bB0, bB1, bB2, bB3)
  }

  // ---- epilogue: add bias, store NCHW ----
#pragma unroll
  for (int j = 0; j < 2; ++j) {
    int o = wv * 32 + j * 16 + row;
    float bo = bias[o];
#pragma unroll
    for (int i = 0; i < 4; ++i) {
      int hw = hw0 + i * 16 + quad * 4;
      float4 v;
      v.x = acc[i][j][0] + bo;
      v.y = acc[i][j][1] + bo;
      v.z = acc[i][j][2] + bo;
      v.w = acc[i][j][3] + bo;
      *(float4*)(out + (((size_t)(b * COUT + o)) << 12) + hw) = v;
    }
  }
}

// ---------------- launch ----------------
extern "C" void kernel_launch(void* const* d_in, const int* in_sizes, int n_in,
                              void* d_out, int out_size, void* d_ws, size_t ws_size,
                              hipStream_t stream) {
  const float* x        = (const float*)d_in[0];
  const float* weight   = (const float*)d_in[1];
  const float* bias     = (const float*)d_in[2];
  const float* p_weight = (const float*)d_in[3];
  const float* p_bias   = (const float*)d_in[4];
  float* out = (float*)d_out;
  char* ws = (char*)d_ws;

  // workspace layout (bytes); total ~9.7 MB
  const size_t OFF_XT   = 0;                          //  8,388,608  bf16 NHWC x
  const size_t OFF_WB   = OFF_XT + 8388608;           //  1,179,648  bf16 WB2
  const size_t OFF_PW   = OFF_WB + 1179648;           //    147,456  bf16
  const size_t OFF_ZP   = OFF_PW + 147456;            //      8,192  zeropage

  unsigned short* xt    = (unsigned short*)(ws + OFF_XT);
  unsigned short* WB    = (unsigned short*)(ws + OFF_WB);
  unsigned short* PWs   = (unsigned short*)(ws + OFF_PW);
  unsigned short* zerop = (unsigned short*)(ws + OFF_ZP);

  prep_and_transpose<<<4096 + 2592, 256, 0, stream>>>(x, weight, p_weight, xt, WB, PWs, zerop);
  fused_gemm<<<256, 512, 0, stream>>>(xt, PWs, p_bias, WB, bias, out);
}

// Round 16
// 123.719 us; speedup vs baseline: 1.3184x; 1.0158x over previous
//
#include <hip/hip_runtime.h>
#include <stdint.h>

// DCNv2 forward, MI355X — R27: rebuild K0 transpose (the new co-dominant cost).
//  R26 (125.68us): pipeline = K0 + fused(51.5). K0 ~45-50us inferred (never
//  in top-5 but total-fused-gaps says so) vs ~13us traffic floor: scalar 4B
//  x-reads + 64B half-line xt writes. R27 K0: 64x64 tiles (1024 blocks),
//  float4 reads (256B/row segments), LDS [64][65] (2-way banks = free both
//  phases), ushort8 packed writes (128B/row segments). Weight-prep blocks
//  unchanged; zerop removed (K1 was its only consumer).
//  fused_gemm byte-identical to R26 (verified).

#define CIN 256
#define COUT 256
#define HWS 4096      // H*W
#define MTOT 16384    // B*H*W
#define KTOT 2304     // CIN*9
#define SPLITK 8

typedef __attribute__((ext_vector_type(8))) short bf16x8;
typedef __attribute__((ext_vector_type(4))) float f32x4;

__device__ __forceinline__ unsigned short f2bf(float f) {
  unsigned int u = __float_as_uint(f);
  unsigned int r = (u + 0x7fffu + ((u >> 16) & 1u)) >> 16;
  return (unsigned short)r;
}
__device__ __forceinline__ float bf2f(unsigned short u) {
  return __uint_as_float(((unsigned int)u) << 16);
}
// bf16 pair unpack: 1 VALU each.
__device__ __forceinline__ float bflo(unsigned int u) { return __uint_as_float(u << 16); }
__device__ __forceinline__ float bfhi(unsigned int u) { return __uint_as_float(u & 0xffff0000u); }

__device__ __forceinline__ void gload_lds16(const void* g, void* l) {
  __builtin_amdgcn_global_load_lds((const __attribute__((address_space(1))) void*)g,
                                   (__attribute__((address_space(3))) void*)l, 16, 0, 0);
}

// Issue-pinned loads; completion via manual counted s_waitcnt + sched fence.
#define GLOAD16(D, P) asm volatile("global_load_dwordx4 %0, %1, off" : "=v"(D) : "v"(P))
#define WAITVM(N)                                            \
  {                                                          \
    asm volatile("s_waitcnt vmcnt(" #N ")" ::: "memory");    \
    __builtin_amdgcn_sched_barrier(0);                       \
  }
#define BARRIER_LGKM                                                  \
  { asm volatile("s_waitcnt lgkmcnt(0)\n\ts_barrier" ::: "memory"); }

// As column swizzle: applied identically on write and read (bits 3..5 only,
// so 16B-aligned 8-element runs stay aligned).
#define ASW(c, rr) ((c) ^ (((rr) & 7) << 3))

// ---------------- K0: fused transpose (64x64 tiles) + weight prep ----------------
__global__ __launch_bounds__(256) void prep_and_transpose(const float* __restrict__ x,
                                                          const float* __restrict__ w,
                                                          const float* __restrict__ pw,
                                                          unsigned short* __restrict__ xt,
                                                          unsigned short* __restrict__ WB,
                                                          unsigned short* __restrict__ PWs) {
  __shared__ float tile[64][65];   // 16,640 B
  int bid = blockIdx.x;
  int tid = threadIdx.x;
  if (bid < 1024) {
    // 64 channels x 64 hw positions per tile.
    int b = bid >> 8;
    int rest = bid & 255;
    int hw0 = (rest & 63) * 64;
    int c0 = (rest >> 6) * 64;
    // read: float4/lane, 16 lanes/row, 16 rows/iter, 4 iters (256B segments)
    {
      int col4 = (tid & 15) * 4;
      int crow = tid >> 4;                   // 0..15
#pragma unroll
      for (int it = 0; it < 4; ++it) {
        int c = it * 16 + crow;
        float4 v = *(const float4*)&x[(size_t)(b * CIN + c0 + c) * HWS + hw0 + col4];
        tile[c][col4] = v.x;
        tile[c][col4 + 1] = v.y;
        tile[c][col4 + 2] = v.z;
        tile[c][col4 + 3] = v.w;
      }
    }
    __syncthreads();
    // write: ushort8 (16B)/lane, 8 lanes/row, 32 rows/iter, 2 iters (128B segments)
    {
      int cc0 = (tid & 7) * 8;
      int rrow = tid >> 3;                   // 0..31
#pragma unroll
      for (int it = 0; it < 2; ++it) {
        int r = it * 32 + rrow;
        uint4 o;
        o.x = (unsigned)f2bf(tile[cc0][r])     | ((unsigned)f2bf(tile[cc0 + 1][r]) << 16);
        o.y = (unsigned)f2bf(tile[cc0 + 2][r]) | ((unsigned)f2bf(tile[cc0 + 3][r]) << 16);
        o.z = (unsigned)f2bf(tile[cc0 + 4][r]) | ((unsigned)f2bf(tile[cc0 + 5][r]) << 16);
        o.w = (unsigned)f2bf(tile[cc0 + 6][r]) | ((unsigned)f2bf(tile[cc0 + 7][r]) << 16);
        *(uint4*)&xt[(size_t)(b * HWS + hw0 + r) * CIN + c0 + cc0] = o;
      }
    }
  } else {
    int idx = (bid - 1024) * 256 + tid;
    if (idx < KTOT * COUT) {
      // WB2[t][j][quad][row][8]: f = (((t*16+j)*4+quad)*16+row)*8+e
      int f = idx;
      int e = f & 7;
      int row = (f >> 3) & 15;
      int quad = (f >> 7) & 3;
      int j = (f >> 9) & 15;
      int t = f >> 13;                 // 0..71
      int kk = t * 32 + quad * 8 + e;
      int o = j * 16 + row;
      int k = kk >> 8, c = kk & 255;
      WB[f] = f2bf(w[o * KTOT + c * 9 + k]);
    } else {
      int f2 = idx - KTOT * COUT;   // < 2304*32
      int t_ = f2 & 7;
      int rest = f2 >> 3;
      int j = rest & 31;
      int kk = (rest >> 5) * 8 + t_;
      int k = kk >> 8, c = kk & 255;
      float v = (j < 27) ? pw[j * KTOT + c * 9 + k] : 0.0f;
      PWs[f2] = f2bf(v);
    }
  }
}

// ---------------- K3: fused offset-conv + index-prep + sample + GEMM ----------------
// (byte-identical to R26's verified kernel)
__device__ __forceinline__ void bilin8p(const uint4 c00, const uint4 c01,
                                        const uint4 c10, const uint4 c11,
                                        const float4 w4, unsigned short* dst) {
  uint4 o;
  float v0, v1;
  v0 = w4.x * bflo(c00.x) + w4.y * bflo(c01.x) + w4.z * bflo(c10.x) + w4.w * bflo(c11.x);
  v1 = w4.x * bfhi(c00.x) + w4.y * bfhi(c01.x) + w4.z * bfhi(c10.x) + w4.w * bfhi(c11.x);
  o.x = (unsigned)f2bf(v0) | ((unsigned)f2bf(v1) << 16);
  v0 = w4.x * bflo(c00.y) + w4.y * bflo(c01.y) + w4.z * bflo(c10.y) + w4.w * bflo(c11.y);
  v1 = w4.x * bfhi(c00.y) + w4.y * bfhi(c01.y) + w4.z * bfhi(c10.y) + w4.w * bfhi(c11.y);
  o.y = (unsigned)f2bf(v0) | ((unsigned)f2bf(v1) << 16);
  v0 = w4.x * bflo(c00.z) + w4.y * bflo(c01.z) + w4.z * bflo(c10.z) + w4.w * bflo(c11.z);
  v1 = w4.x * bfhi(c00.z) + w4.y * bfhi(c01.z) + w4.z * bfhi(c10.z) + w4.w * bfhi(c11.z);
  o.z = (unsigned)f2bf(v0) | ((unsigned)f2bf(v1) << 16);
  v0 = w4.x * bflo(c00.w) + w4.y * bflo(c01.w) + w4.z * bflo(c10.w) + w4.w * bflo(c11.w);
  v1 = w4.x * bfhi(c00.w) + w4.y * bfhi(c01.w) + w4.z * bfhi(c10.w) + w4.w * bfhi(c11.w);
  o.w = (unsigned)f2bf(v0) | ((unsigned)f2bf(v1) << 16);
  *(uint4*)dst = o;
}

#define MFMA16P(B0, B1, B2, B3)                                                          \
  acc[0][0] = __builtin_amdgcn_mfma_f32_16x16x32_bf16(afr0, B0, acc[0][0], 0, 0, 0);     \
  acc[0][1] = __builtin_amdgcn_mfma_f32_16x16x32_bf16(afr0, B1, acc[0][1], 0, 0, 0);     \
  acc[1][0] = __builtin_amdgcn_mfma_f32_16x16x32_bf16(afr1, B0, acc[1][0], 0, 0, 0);     \
  acc[1][1] = __builtin_amdgcn_mfma_f32_16x16x32_bf16(afr1, B1, acc[1][1], 0, 0, 0);     \
  acc[2][0] = __builtin_amdgcn_mfma_f32_16x16x32_bf16(afr2, B0, acc[2][0], 0, 0, 0);     \
  acc[2][1] = __builtin_amdgcn_mfma_f32_16x16x32_bf16(afr2, B1, acc[2][1], 0, 0, 0);     \
  acc[3][0] = __builtin_amdgcn_mfma_f32_16x16x32_bf16(afr3, B0, acc[3][0], 0, 0, 0);     \
  acc[3][1] = __builtin_amdgcn_mfma_f32_16x16x32_bf16(afr3, B1, acc[3][1], 0, 0, 0);     \
  acc[0][0] = __builtin_amdgcn_mfma_f32_16x16x32_bf16(afr4, B2, acc[0][0], 0, 0, 0);     \
  acc[0][1] = __builtin_amdgcn_mfma_f32_16x16x32_bf16(afr4, B3, acc[0][1], 0, 0, 0);     \
  acc[1][0] = __builtin_amdgcn_mfma_f32_16x16x32_bf16(afr5, B2, acc[1][0], 0, 0, 0);     \
  acc[1][1] = __builtin_amdgcn_mfma_f32_16x16x32_bf16(afr5, B3, acc[1][1], 0, 0, 0);     \
  acc[2][0] = __builtin_amdgcn_mfma_f32_16x16x32_bf16(afr6, B2, acc[2][0], 0, 0, 0);     \
  acc[2][1] = __builtin_amdgcn_mfma_f32_16x16x32_bf16(afr6, B3, acc[2][1], 0, 0, 0);     \
  acc[3][0] = __builtin_amdgcn_mfma_f32_16x16x32_bf16(afr7, B2, acc[3][0], 0, 0, 0);     \
  acc[3][1] = __builtin_amdgcn_mfma_f32_16x16x32_bf16(afr7, B3, acc[3][1], 0, 0, 0);

// Steady period P. GI* receive G(P+2 data); GC* hold G(P+1) (issued at P-1).
// BI* receive B(P+1); BC* hold B(P) (issued at P-1, oldest in flight).
#define FITER_P2(P, PAR, GI0, GI1, GI2, GI3, GC0, GC1, GC2, GC3,                         \
                 BC0, BC1, BC2, BC3, BI0, BI1, BI2, BI3)                                 \
  {                                                                                      \
    const unsigned short* btn = bpb + (size_t)(2 * ((P) + 1)) * 8192;                    \
    GLOAD16(BI0, btn);                                                                   \
    GLOAD16(BI1, btn + 512);                                                             \
    GLOAD16(BI2, btn + 8192);                                                            \
    GLOAD16(BI3, btn + 8192 + 512);                                                      \
    if ((((P) + 2) & 3) == 0) dI4 = Tbl[r][((P) + 2) >> 2][0];                           \
    int cb = ((2 * (P) + 4) & 7) * 32 + qo8;                                             \
    GLOAD16(GI0, xtb + dI4.x + cb);                                                      \
    GLOAD16(GI1, xtb + dI4.y + cb);                                                      \
    GLOAD16(GI2, xtb + dI4.z + cb);                                                      \
    GLOAD16(GI3, xtb + dI4.w + cb);                                                      \
    afr0 = *(const bf16x8*)&As[PAR][row][ASW(quad * 8, row)];                            \
    afr1 = *(const bf16x8*)&As[PAR][16 + row][ASW(quad * 8, row)];                       \
    afr2 = *(const bf16x8*)&As[PAR][32 + row][ASW(quad * 8, row)];                       \
    afr3 = *(const bf16x8*)&As[PAR][48 + row][ASW(quad * 8, row)];                       \
    afr4 = *(const bf16x8*)&As[PAR][row][ASW(32 + quad * 8, row)];                       \
    afr5 = *(const bf16x8*)&As[PAR][16 + row][ASW(32 + quad * 8, row)];                  \
    afr6 = *(const bf16x8*)&As[PAR][32 + row][ASW(32 + quad * 8, row)];                  \
    afr7 = *(const bf16x8*)&As[PAR][48 + row][ASW(32 + quad * 8, row)];                  \
    if ((((P) + 1) & 3) == 0) dW4 = *(float4*)&Tbl[r][((P) + 1) >> 2][1];                \
    WAITVM(12)                                                                           \
    MFMA16P(BC0, BC1, BC2, BC3)                                                          \
    WAITVM(8)                                                                            \
    bilin8p(GC0, GC1, GC2, GC3, dW4, &As[PAR ^ 1][r][ASW(qo8, r)]);                      \
    BARRIER_LGKM                                                                         \
  }

__global__ __launch_bounds__(512, 2) void fused_gemm(const unsigned short* __restrict__ xt,
                                                     const unsigned short* __restrict__ PWs,
                                                     const float* __restrict__ p_bias,
                                                     const unsigned short* __restrict__ WB,
                                                     const float* __restrict__ bias,
                                                     float* __restrict__ out) {
  __shared__ unsigned short As[2][64][64];   // 16,384 B, XOR-swizzled columns
  __shared__ int4 Tbl[64][9][2];             // 18,432 B [r][tap]{dI, dW}
  __shared__ float Ptl[8][64][32];           // 65,536 B offset-conv partials

  int tid = threadIdx.x;
  int lane = tid & 63, wv = tid >> 6;        // 8 waves
  int row = lane & 15, quad = lane >> 4;
  int mt = (blockIdx.x & 7) * 32 + (blockIdx.x >> 3);   // XCD-chunked swizzle
  int mb = mt * 64;
  int b = mb >> 12;
  int hw0 = mb & 4095;
  const unsigned short* xtb = xt + ((size_t)b << 20);

  // ---- (a) offset conv (ex-K1): wave wv covers k-tiles 9wv..9wv+8 ----
  {
    f32x4 aco[4][2] = {};
    for (int tt = 0; tt < 9; ++tt) {
      int t = wv * 9 + tt;
      int k = t >> 3, c0 = (t & 7) * 32;
      int dyk = k / 3 - 1, dxk = k % 3 - 1;
      const unsigned short* pb = PWs + (size_t)t * 1024 + (quad * 32 + row) * 8;
      bf16x8 ob0 = *(const bf16x8*)pb;           // j=0
      bf16x8 ob1 = *(const bf16x8*)(pb + 128);   // j=1 (+16 rows * 8)
#pragma unroll
      for (int rs = 0; rs < 4; ++rs) {
        int hw = hw0 + rs * 16 + row;
        int h = hw >> 6, wq = hw & 63;
        int y = h + dyk, xx = wq + dxk;
        bf16x8 oa = {};
        if (((unsigned)y < 64u) && ((unsigned)xx < 64u))
          oa = *(const bf16x8*)(xtb + (size_t)(((y << 6) + xx) << 8) + c0 + quad * 8);
        aco[rs][0] = __builtin_amdgcn_mfma_f32_16x16x32_bf16(oa, ob0, aco[rs][0], 0, 0, 0);
        aco[rs][1] = __builtin_amdgcn_mfma_f32_16x16x32_bf16(oa, ob1, aco[rs][1], 0, 0, 0);
      }
    }
#pragma unroll
    for (int rs = 0; rs < 4; ++rs)
#pragma unroll
      for (int j = 0; j < 2; ++j)
#pragma unroll
        for (int e = 0; e < 4; ++e)
          Ptl[wv][rs * 16 + quad * 4 + e][j * 16 + row] = aco[rs][j][e];
  }
  __syncthreads();

  // ---- (b) reduce 8 waves' partials into Ptl[0] ----
  for (int i = tid; i < 2048; i += 512) {
    int lm = i >> 5, n = i & 31;
    float s = Ptl[0][lm][n];
#pragma unroll
    for (int w = 1; w < 8; ++w) s += Ptl[w][lm][n];
    Ptl[0][lm][n] = s;
  }
  __syncthreads();

  // ---- (c) index prep (ex-K2): 576 (row, tap) pairs over 512 threads ----
  for (int pr = tid; pr < 576; pr += 512) {
    int lm = pr / 9;
    int k = pr - lm * 9;
    int m = mb + lm;

    float dy = p_bias[2 * k] + Ptl[0][lm][2 * k];
    float dx = p_bias[2 * k + 1] + Ptl[0][lm][2 * k + 1];
    float mv = p_bias[18 + k] + Ptl[0][lm][18 + k];
    float mk = 1.0f / (1.0f + __expf(-mv));

    int hw = m & 4095, h = hw >> 6, ww = hw & 63;
    float py = (float)(h - 1 + k / 3) + dy;
    float px = (float)(ww - 1 + k % 3) + dx;
    float y0f = floorf(py), x0f = floorf(px);
    float ay = py - y0f, ax = px - x0f;
    int y0 = (int)y0f, x0 = (int)x0f;

    float w00 = (1.f - ay) * (1.f - ax) * mk;
    float w01 = (1.f - ay) * ax * mk;
    float w10 = ay * (1.f - ax) * mk;
    float w11 = ay * ax * mk;

    float vy0 = ((unsigned)y0 < 64u) ? 1.f : 0.f;
    float vy1 = ((unsigned)(y0 + 1) < 64u) ? 1.f : 0.f;
    float vx0 = ((unsigned)x0 < 64u) ? 1.f : 0.f;
    float vx1 = ((unsigned)(x0 + 1) < 64u) ? 1.f : 0.f;
    w00 *= vy0 * vx0; w01 *= vy0 * vx1; w10 *= vy1 * vx0; w11 *= vy1 * vx1;

    int yc0 = min(max(y0, 0), 63), yc1 = min(max(y0 + 1, 0), 63);
    int xc0 = min(max(x0, 0), 63), xc1 = min(max(x0 + 1, 0), 63);

    Tbl[lm][k][0] = make_int4((yc0 * 64 + xc0) * 256, (yc0 * 64 + xc1) * 256,
                              (yc1 * 64 + xc0) * 256, (yc1 * 64 + xc1) * 256);
    *(float4*)&Tbl[lm][k][1] = make_float4(w00, w01, w10, w11);
  }
  __syncthreads();   // full drain (vmcnt+lgkm) BEFORE any pinned loads

  int r = tid >> 3;         // sampler row 0..63 (8 threads/row)
  int qo8 = (tid & 7) * 8;  // sampler channel sub-block (8 ch, 16 B)

  int4 dI4 = Tbl[r][0][0];
  float4 dW4 = *(float4*)&Tbl[r][0][1];

  const unsigned short* bpb = WB + (size_t)(wv * 2) * 512 + quad * 128 + row * 8;

  f32x4 acc[4][2] = {};
  uint4 gA0, gA1, gA2, gA3;            // even-period gather set
  uint4 gB0, gB1, gB2, gB3;            // odd-period gather set
  bf16x8 bA0, bA1, bA2, bA3;           // even-period B set
  bf16x8 bB0, bB1, bB2, bB3;           // odd-period B set
  bf16x8 afr0, afr1, afr2, afr3, afr4, afr5, afr6, afr7;

  // ---- prologue: sample period 0 via compiler loads; pin B(0), G(1) ----
  {
    uint4 p00 = *(const uint4*)(xtb + dI4.x + qo8);
    uint4 p01 = *(const uint4*)(xtb + dI4.y + qo8);
    uint4 p10 = *(const uint4*)(xtb + dI4.z + qo8);
    uint4 p11 = *(const uint4*)(xtb + dI4.w + qo8);
    bilin8p(p00, p01, p10, p11, dW4, &As[0][r][ASW(qo8, r)]);
    // pinned issues, ORDER: B(0) x4 first (oldest), then G(1) x4
    GLOAD16(bA0, bpb);
    GLOAD16(bA1, bpb + 512);
    GLOAD16(bA2, bpb + 8192);
    GLOAD16(bA3, bpb + 8192 + 512);
    int cb1 = 64 + qo8;   // period 1 = tiles 2,3 (ch 64..127), tap 0
    GLOAD16(gA0, xtb + dI4.x + cb1);
    GLOAD16(gA1, xtb + dI4.y + cb1);
    GLOAD16(gA2, xtb + dI4.z + cb1);
    GLOAD16(gA3, xtb + dI4.w + cb1);
  }
  BARRIER_LGKM   // As[0] visible; 8 pinned loads in flight

  // ---- steady loop: periods 0..33 ----
#pragma unroll 1
  for (int p = 0; p < 34; p += 2) {
    FITER_P2(p,     0, gB0, gB1, gB2, gB3, gA0, gA1, gA2, gA3,
                       bA0, bA1, bA2, bA3, bB0, bB1, bB2, bB3)
    FITER_P2(p + 1, 1, gA0, gA1, gA2, gA3, gB0, gB1, gB2, gB3,
                       bB0, bB1, bB2, bB3, bA0, bA1, bA2, bA3)
  }

  // ---- peeled P=34 (PAR=0): BC=bA=B(34), GC=gA=G(35); issue B(35)->bB ----
  {
    const unsigned short* btn = bpb + (size_t)70 * 8192;
    GLOAD16(bB0, btn);
    GLOAD16(bB1, btn + 512);
    GLOAD16(bB2, btn + 8192);
    GLOAD16(bB3, btn + 8192 + 512);
    afr0 = *(const bf16x8*)&As[0][row][ASW(quad * 8, row)];
    afr1 = *(const bf16x8*)&As[0][16 + row][ASW(quad * 8, row)];
    afr2 = *(const bf16x8*)&As[0][32 + row][ASW(quad * 8, row)];
    afr3 = *(const bf16x8*)&As[0][48 + row][ASW(quad * 8, row)];
    afr4 = *(const bf16x8*)&As[0][row][ASW(32 + quad * 8, row)];
    afr5 = *(const bf16x8*)&As[0][16 + row][ASW(32 + quad * 8, row)];
    afr6 = *(const bf16x8*)&As[0][32 + row][ASW(32 + quad * 8, row)];
    afr7 = *(const bf16x8*)&As[0][48 + row][ASW(32 + quad * 8, row)];
    WAITVM(8)    // drains B(34)
    MFMA16P(bA0, bA1, bA2, bA3)
    WAITVM(4)    // drains G(35)
    bilin8p(gA0, gA1, gA2, gA3, dW4, &As[1][r][ASW(qo8, r)]);   // dW4 = tap 8
    BARRIER_LGKM
  }
  // ---- peeled P=35 (PAR=1): BC=bB=B(35); no bilin ----
  {
    afr0 = *(const bf16x8*)&As[1][row][ASW(quad * 8, row)];
    afr1 = *(const bf16x8*)&As[1][16 + row][ASW(quad * 8, row)];
    afr2 = *(const bf16x8*)&As[1][32 + row][ASW(quad * 8, row)];
    afr3 = *(const bf16x8*)&As[1][48 + row][ASW(quad * 8, row)];
    afr4 = *(const bf16x8*)&As[1][row][ASW(32 + quad * 8, row)];
    afr5 = *(const bf16x8*)&As[1][16 + row][ASW(32 + quad * 8, row)];
    afr6 = *(const bf16x8*)&As[1][32 + row][ASW(32 + quad * 8, row)];
    afr7 = *(const bf16x8*)&As[1][48 + row][ASW(32 + quad * 8, row)];
    WAITVM(0)
    MFMA16P(bB0, bB1, bB2, bB3)
  }

  // ---- epilogue: add bias, store NCHW ----
#pragma unroll
  for (int j = 0; j < 2; ++j) {
    int o = wv * 32 + j * 16 + row;
    float bo = bias[o];
#pragma unroll
    for (int i = 0; i < 4; ++i) {
      int hw = hw0 + i * 16 + quad * 4;
      float4 v;
      v.x = acc[i][j][0] + bo;
      v.y = acc[i][j][1] + bo;
      v.z = acc[i][j][2] + bo;
      v.w = acc[i][j][3] + bo;
      *(float4*)(out + (((size_t)(b * COUT + o)) << 12) + hw) = v;
    }
  }
}

// ---------------- launch ----------------
extern "C" void kernel_launch(void* const* d_in, const int* in_sizes, int n_in,
                              void* d_out, int out_size, void* d_ws, size_t ws_size,
                              hipStream_t stream) {
  const float* x        = (const float*)d_in[0];
  const float* weight   = (const float*)d_in[1];
  const float* bias     = (const float*)d_in[2];
  const float* p_weight = (const float*)d_in[3];
  const float* p_bias   = (const float*)d_in[4];
  float* out = (float*)d_out;
  char* ws = (char*)d_ws;

  // workspace layout (bytes); total ~9.7 MB
  const size_t OFF_XT   = 0;                          //  8,388,608  bf16 NHWC x
  const size_t OFF_WB   = OFF_XT + 8388608;           //  1,179,648  bf16 WB2
  const size_t OFF_PW   = OFF_WB + 1179648;           //    147,456  bf16

  unsigned short* xt    = (unsigned short*)(ws + OFF_XT);
  unsigned short* WB    = (unsigned short*)(ws + OFF_WB);
  unsigned short* PWs   = (unsigned short*)(ws + OFF_PW);

  prep_and_transpose<<<1024 + 2592, 256, 0, stream>>>(x, weight, p_weight, xt, WB, PWs);
  fused_gemm<<<256, 512, 0, stream>>>(xt, PWs, p_bias, WB, bias, out);
}